// Round 1
// baseline (443.482 us; speedup 1.0000x reference)
//
#include <hip/hip_runtime.h>
#include <math.h>

#define SEQ   1024
#define DQ    256
#define DVD   512
#define NHH   16          // B*NH
#define EPSF  1e-6f
#define INV_SQRT_D 0.0625f   // 1/sqrt(256)

// ---- workspace layout (float offsets) ----
#define WS_FG    0                        // [16][1024]
#define WS_IG    (NHH*SEQ)                // [16][1024]
#define WS_ELIM  (2*NHH*SEQ)              // [16][1024]  exp(-m_t)
#define WS_HDEN  (3*NHH*SEQ)              // [16][1024]
#define WS_AC    (4*NHH*SEQ)              // [16][16]   per-chunk decay product
#define WS_BVEC  (WS_AC + NHH*16)         // [16][16][256]
#define WS_NST   (WS_BVEC + NHH*16*DQ)    // [16][16][256]
// total = 4*16384 + 256 + 2*65536 = 196,864 floats = 787,456 bytes

// ============================================================
// Kernel A: gates. m_t recurrence is a max-plus scan:
//   F_t = prefix_sum(log_sigmoid(f));  m_t = F_t + max(0, prefix_max(i_s - F_s))
// Emits fg, ig, exp(-m_t), final m, and per-64-chunk decay A_c (telescoped).
// ============================================================
__global__ __launch_bounds__(1024) void gates_kernel(
    const float* __restrict__ ipre, const float* __restrict__ fpre,
    float* __restrict__ ws, float* __restrict__ m_out) {
  const int hh = blockIdx.x;
  const int t  = threadIdx.x;
  __shared__ float sc[SEQ];
  __shared__ float Fs[SEQ];
  __shared__ float Ms[SEQ];

  const float fp = fpre[hh*SEQ + t];
  const float ip = ipre[hh*SEQ + t];
  // stable log_sigmoid
  const float flog = fminf(fp, 0.f) - log1pf(expf(-fabsf(fp)));

  // inclusive prefix sum of flog (Hillis-Steele)
  float val = flog;
  sc[t] = val; __syncthreads();
  for (int off = 1; off < SEQ; off <<= 1) {
    const float other = (t >= off) ? sc[t - off] : 0.f;
    __syncthreads();
    val += other; sc[t] = val; __syncthreads();
  }
  const float F = val;
  Fs[t] = F;

  // inclusive prefix max of z = ip - F
  float zv = ip - F;
  sc[t] = zv; __syncthreads();
  for (int off = 1; off < SEQ; off <<= 1) {
    const float other = (t >= off) ? sc[t - off] : -INFINITY;
    __syncthreads();
    zv = fmaxf(zv, other); sc[t] = zv; __syncthreads();
  }

  const float m_t = F + fmaxf(zv, 0.f);
  Ms[t] = m_t; __syncthreads();
  const float m_prev = (t == 0) ? 0.f : Ms[t - 1];

  ws[WS_FG   + hh*SEQ + t] = expf(flog + m_prev - m_t);
  ws[WS_IG   + hh*SEQ + t] = expf(ip - m_t);
  ws[WS_ELIM + hh*SEQ + t] = expf(-m_t);
  if (t == SEQ - 1) m_out[hh] = m_t;
  if ((t & 63) == 63) {   // chunk decay: prod of fg over chunk, via telescoped sum
    const int c = t >> 6;
    const float Fprev  = (c == 0) ? 0.f : Fs[t - 64];
    const float mprevc = (c == 0) ? 0.f : Ms[t - 64];
    ws[WS_AC + hh*16 + c] = expf((F - Fprev) + (mprevc - m_t));
  }
}

// ============================================================
// Kernel B1: per-(head,chunk) rank update B_c[d] = sum_s decay * ig_s k_s[d]
// ============================================================
__global__ __launch_bounds__(256) void bvec_kernel(
    const float* __restrict__ kin, float* __restrict__ ws) {
  const int hh = blockIdx.x >> 4;
  const int c  = blockIdx.x & 15;
  const int d  = threadIdx.x;
  __shared__ float lk[64][DQ];          // 64 KB
  const int base = (hh*SEQ + c*64) * DQ;
  #pragma unroll 4
  for (int tt = 0; tt < 64; ++tt) lk[tt][d] = kin[base + tt*DQ + d];
  __syncthreads();
  float nb = 0.f;
  const float* fg = ws + WS_FG + hh*SEQ + c*64;
  const float* ig = ws + WS_IG + hh*SEQ + c*64;
  #pragma unroll 8
  for (int tt = 0; tt < 64; ++tt) nb = fg[tt]*nb + ig[tt]*lk[tt][d];
  ws[WS_BVEC + (hh*16 + c)*DQ + d] = nb;
}

// ============================================================
// Kernel B2: 16-step chunk scan of n; emits n at each chunk start + final n
// ============================================================
__global__ __launch_bounds__(256) void nscan_kernel(
    float* __restrict__ ws, float* __restrict__ n_out) {
  const int hh = blockIdx.x;
  const int d  = threadIdx.x;
  float n = 0.f;
  for (int c = 0; c < 16; ++c) {
    ws[WS_NST + (hh*16 + c)*DQ + d] = n;
    n = ws[WS_AC + hh*16 + c]*n + ws[WS_BVEC + (hh*16 + c)*DQ + d];
  }
  n_out[hh*DQ + d] = n;
}

// ============================================================
// Kernel B3: per-(head,chunk) recompute n_t in-chunk, qn_dot reduce, h_den
// ============================================================
__global__ __launch_bounds__(256) void hden_kernel(
    const float* __restrict__ kin, const float* __restrict__ qin,
    float* __restrict__ ws) {
  const int hh = blockIdx.x >> 4;
  const int c  = blockIdx.x & 15;
  const int d  = threadIdx.x;
  __shared__ float pbuf[64][DQ];        // 64 KB
  float n = ws[WS_NST + (hh*16 + c)*DQ + d];
  const int tbase = hh*SEQ + c*64;
  const int base  = tbase * DQ;
  #pragma unroll 4
  for (int tt = 0; tt < 64; ++tt) {
    const float fg = ws[WS_FG + tbase + tt];
    const float ig = ws[WS_IG + tbase + tt];
    n = fg*n + ig*kin[base + tt*DQ + d];
    pbuf[tt][d] = n * qin[base + tt*DQ + d];
  }
  __syncthreads();
  if (d < 64) {   // one t per thread; rotated reads avoid 64-way bank conflict
    float s = 0.f;
    #pragma unroll 8
    for (int jj = 0; jj < DQ; ++jj) s += pbuf[d][(d + jj) & (DQ - 1)];
    const float qn = s * INV_SQRT_D;
    const float hd = fmaxf(fabsf(qn), ws[WS_ELIM + tbase + d]) + EPSF;
    ws[WS_HDEN + tbase + d] = hd;
  }
}

// ============================================================
// Main kernel: 16 heads x 16 DV-chunks of 32. 256 thr: (vl = tid&31, dg = tid>>5).
// Each thread holds C[dg*32+j][v] j<32 in registers. k/q/v staged in LDS per
// 16-step batch; h partials reduced through LDS pbuf. 2 barriers / 16 steps.
// ============================================================
__global__ __launch_bounds__(256) void mlstm_main_kernel(
    const float* __restrict__ qin, const float* __restrict__ kin,
    const float* __restrict__ vin, const float* __restrict__ ws,
    float* __restrict__ h_out, float* __restrict__ C_out) {
  const int hh  = blockIdx.x >> 4;
  const int ch  = blockIdx.x & 15;
  const int tid = threadIdx.x;
  const int vl  = tid & 31;
  const int dg  = tid >> 5;

  __shared__ float lk[16][DQ];          // 16 KB
  __shared__ float lq[16][DQ];          // 16 KB
  __shared__ float lv[16][32];          //  2 KB
  __shared__ float pbuf[16][8][32];     // 16 KB

  float c[32];
  #pragma unroll
  for (int j = 0; j < 32; ++j) c[j] = 0.f;

  for (int ob = 0; ob < 64; ++ob) {
    const int t0 = ob * 16;
    const int gbase = (hh*SEQ + t0) * DQ;
    #pragma unroll 4
    for (int r = 0; r < 16; ++r) {
      lk[r][tid] = kin[gbase + r*DQ + tid];
      lq[r][tid] = qin[gbase + r*DQ + tid];
    }
    {
      const int vgbase = (hh*SEQ + t0) * DVD + ch*32;
      #pragma unroll
      for (int r2 = 0; r2 < 2; ++r2) {
        const int j = r2*256 + tid;
        lv[j >> 5][j & 31] = vin[vgbase + (j >> 5)*DVD + (j & 31)];
      }
    }
    __syncthreads();

    for (int tt = 0; tt < 16; ++tt) {
      const int t = t0 + tt;
      const float fg  = ws[WS_FG + hh*SEQ + t];
      const float ig  = ws[WS_IG + hh*SEQ + t];
      const float ivv = ig * lv[tt][vl];
      const float4* kp = (const float4*)(&lk[tt][dg*32]);
      const float4* qp = (const float4*)(&lq[tt][dg*32]);
      float part = 0.f;
      #pragma unroll
      for (int j4 = 0; j4 < 8; ++j4) {
        const float4 kk = kp[j4];
        const float4 qq = qp[j4];
        c[j4*4+0] = fg*c[j4*4+0] + ivv*kk.x; part += c[j4*4+0]*qq.x;
        c[j4*4+1] = fg*c[j4*4+1] + ivv*kk.y; part += c[j4*4+1]*qq.y;
        c[j4*4+2] = fg*c[j4*4+2] + ivv*kk.z; part += c[j4*4+2]*qq.z;
        c[j4*4+3] = fg*c[j4*4+3] + ivv*kk.w; part += c[j4*4+3]*qq.w;
      }
      pbuf[tt][dg][vl] = part;
    }
    __syncthreads();

    #pragma unroll
    for (int rep = 0; rep < 2; ++rep) {
      const int idx = rep*256 + tid;
      const int tt  = idx >> 5;
      const int v2  = idx & 31;
      float s = 0.f;
      #pragma unroll
      for (int g = 0; g < 8; ++g) s += pbuf[tt][g][v2];
      const float hd = ws[WS_HDEN + hh*SEQ + t0 + tt];
      h_out[(hh*SEQ + t0 + tt)*DVD + ch*32 + v2] = s * INV_SQRT_D / hd;
    }
    // next iteration's staging (lk/lq/lv) doesn't touch pbuf; compute(i+1)
    // writes pbuf only after the post-stage barrier -> 2 barriers per batch.
  }

  #pragma unroll
  for (int j = 0; j < 32; ++j) {
    const int d = dg*32 + j;
    C_out[(hh*DQ + d)*DVD + ch*32 + vl] = c[j];
  }
}

// ============================================================
extern "C" void kernel_launch(void* const* d_in, const int* in_sizes, int n_in,
                              void* d_out, int out_size, void* d_ws, size_t ws_size,
                              hipStream_t stream) {
  const float* q  = (const float*)d_in[0];
  const float* k  = (const float*)d_in[1];
  const float* v  = (const float*)d_in[2];
  const float* ip = (const float*)d_in[3];
  const float* fp = (const float*)d_in[4];

  float* h_out = (float*)d_out;                       // [16][1024][512]
  float* C_out = h_out + NHH*SEQ*DVD;                 // [16][256][512]
  float* n_out = C_out + NHH*DQ*DVD;                  // [16][256]
  float* m_out = n_out + NHH*DQ;                      // [16]
  float* ws    = (float*)d_ws;                        // needs ~788 KB

  gates_kernel<<<NHH, 1024, 0, stream>>>(ip, fp, ws, m_out);
  bvec_kernel<<<NHH*16, 256, 0, stream>>>(k, ws);
  nscan_kernel<<<NHH, 256, 0, stream>>>(ws, n_out);
  hden_kernel<<<NHH*16, 256, 0, stream>>>(k, q, ws);
  mlstm_main_kernel<<<NHH*16, 256, 0, stream>>>(q, k, v, ws, h_out, C_out);
}

// Round 2
// 124.294 us; speedup vs baseline: 3.5680x; 3.5680x over previous
//
#include <hip/hip_runtime.h>
#include <math.h>

#define SEQ   1024
#define DQ    256
#define DVD   512
#define NHH   16          // B*NH
#define EPSF  1e-6f
#define INV_SQRT_D 0.0625f   // 1/sqrt(256)

typedef __attribute__((ext_vector_type(8)))  short short8v;
typedef __attribute__((ext_vector_type(16))) float f32x16;

// ---- workspace layout (float offsets) ----
#define WS_FG    0                        // [16][1024]
#define WS_IG    (NHH*SEQ)                // [16][1024]
#define WS_ELIM  (2*NHH*SEQ)              // [16][1024]  exp(-m_t)
#define WS_HDEN  (3*NHH*SEQ)              // [16][1024]
#define WS_AC    (4*NHH*SEQ)              // [16][16]
#define WS_BVEC  (WS_AC + NHH*16)         // [16][16][256]
#define WS_NST   (WS_BVEC + NHH*16*DQ)    // [16][16][256]
#define WS_AT    (WS_NST + NHH*16*DQ)     // [16][1024]  a_t = F_t - m_t
#define WS_CS    (WS_AT + NHH*SEQ)        // [16][1024]  c_s = i_s - F_s
#define WS_UT    (WS_CS + NHH*SEQ)        // [16][1024]  u_t (final C weight)
#define WS_SMALL_FLOATS (WS_UT + NHH*SEQ) // 246016 floats

#define QBF_OFF  ((size_t)WS_SMALL_FLOATS * 4)             // bytes
#define KBF_OFF  (QBF_OFF + (size_t)NHH*SEQ*DQ*2)
#define VTB_OFF  (KBF_OFF + (size_t)NHH*SEQ*DQ*2)
#define KUT_OFF  (VTB_OFF + (size_t)NHH*DVD*SEQ*2)
#define WS_NEED  (KUT_OFF + (size_t)NHH*DQ*SEQ*2)

__device__ __forceinline__ unsigned short f2bf(float f) {
  unsigned int u = __float_as_uint(f);
  return (unsigned short)((u + 0x7fffu + ((u >> 16) & 1u)) >> 16);
}

__device__ __forceinline__ void gl_lds16(const void* g, void* l) {
  __builtin_amdgcn_global_load_lds(
      (const __attribute__((address_space(1))) unsigned int*)g,
      (__attribute__((address_space(3))) unsigned int*)l, 16, 0, 0);
}

// ============================================================
// Kernel A: gates (max-plus scan). Also emits a_t, c_s, u_t.
// ============================================================
__global__ __launch_bounds__(1024) void gates_kernel(
    const float* __restrict__ ipre, const float* __restrict__ fpre,
    float* __restrict__ ws, float* __restrict__ m_out) {
  const int hh = blockIdx.x;
  const int t  = threadIdx.x;
  __shared__ float sc[SEQ];
  __shared__ float Fs[SEQ];
  __shared__ float Ms[SEQ];

  const float fp = fpre[hh*SEQ + t];
  const float ip = ipre[hh*SEQ + t];
  const float flog = fminf(fp, 0.f) - log1pf(expf(-fabsf(fp)));

  float val = flog;
  sc[t] = val; __syncthreads();
  for (int off = 1; off < SEQ; off <<= 1) {
    const float other = (t >= off) ? sc[t - off] : 0.f;
    __syncthreads();
    val += other; sc[t] = val; __syncthreads();
  }
  const float F = val;
  Fs[t] = F;

  float zv = ip - F;
  sc[t] = zv; __syncthreads();
  for (int off = 1; off < SEQ; off <<= 1) {
    const float other = (t >= off) ? sc[t - off] : -INFINITY;
    __syncthreads();
    zv = fmaxf(zv, other); sc[t] = zv; __syncthreads();
  }

  const float m_t = F + fmaxf(zv, 0.f);
  Ms[t] = m_t; __syncthreads();
  const float m_prev = (t == 0) ? 0.f : Ms[t - 1];
  const float F_end = Fs[SEQ-1];
  const float m_end = Ms[SEQ-1];

  ws[WS_FG   + hh*SEQ + t] = expf(flog + m_prev - m_t);
  ws[WS_IG   + hh*SEQ + t] = expf(ip - m_t);
  ws[WS_ELIM + hh*SEQ + t] = expf(-m_t);
  ws[WS_AT   + hh*SEQ + t] = F - m_t;
  ws[WS_CS   + hh*SEQ + t] = ip - F;
  ws[WS_UT   + hh*SEQ + t] = expf(F_end - F + ip - m_end);
  if (t == SEQ - 1) m_out[hh] = m_t;
  if ((t & 63) == 63) {
    const int c = t >> 6;
    const float Fprev  = (c == 0) ? 0.f : Fs[t - 64];
    const float mprevc = (c == 0) ? 0.f : Ms[t - 64];
    ws[WS_AC + hh*16 + c] = expf((F - Fprev) + (mprevc - m_t));
  }
}

// ============================================================
// B1/B2/B3: exact fp32 denominator pipeline (unchanged, verified)
// ============================================================
__global__ __launch_bounds__(256) void bvec_kernel(
    const float* __restrict__ kin, float* __restrict__ ws) {
  const int hh = blockIdx.x >> 4;
  const int c  = blockIdx.x & 15;
  const int d  = threadIdx.x;
  __shared__ float lk[64][DQ];
  const int base = (hh*SEQ + c*64) * DQ;
  #pragma unroll 4
  for (int tt = 0; tt < 64; ++tt) lk[tt][d] = kin[base + tt*DQ + d];
  __syncthreads();
  float nb = 0.f;
  const float* fg = ws + WS_FG + hh*SEQ + c*64;
  const float* ig = ws + WS_IG + hh*SEQ + c*64;
  #pragma unroll 8
  for (int tt = 0; tt < 64; ++tt) nb = fg[tt]*nb + ig[tt]*lk[tt][d];
  ws[WS_BVEC + (hh*16 + c)*DQ + d] = nb;
}

__global__ __launch_bounds__(256) void nscan_kernel(
    float* __restrict__ ws, float* __restrict__ n_out) {
  const int hh = blockIdx.x;
  const int d  = threadIdx.x;
  float n = 0.f;
  for (int c = 0; c < 16; ++c) {
    ws[WS_NST + (hh*16 + c)*DQ + d] = n;
    n = ws[WS_AC + hh*16 + c]*n + ws[WS_BVEC + (hh*16 + c)*DQ + d];
  }
  n_out[hh*DQ + d] = n;
}

__global__ __launch_bounds__(256) void hden_kernel(
    const float* __restrict__ kin, const float* __restrict__ qin,
    float* __restrict__ ws) {
  const int hh = blockIdx.x >> 4;
  const int c  = blockIdx.x & 15;
  const int d  = threadIdx.x;
  __shared__ float pbuf[64][DQ];
  float n = ws[WS_NST + (hh*16 + c)*DQ + d];
  const int tbase = hh*SEQ + c*64;
  const int base  = tbase * DQ;
  #pragma unroll 4
  for (int tt = 0; tt < 64; ++tt) {
    const float fg = ws[WS_FG + tbase + tt];
    const float ig = ws[WS_IG + tbase + tt];
    n = fg*n + ig*kin[base + tt*DQ + d];
    pbuf[tt][d] = n * qin[base + tt*DQ + d];
  }
  __syncthreads();
  if (d < 64) {
    float s = 0.f;
    #pragma unroll 8
    for (int jj = 0; jj < DQ; ++jj) s += pbuf[d][(d + jj) & (DQ - 1)];
    const float qn = s * INV_SQRT_D;
    const float hd = fmaxf(fabsf(qn), ws[WS_ELIM + tbase + d]) + EPSF;
    ws[WS_HDEN + tbase + d] = hd;
  }
}

// ============================================================
// Cast: q_bf = bf16(q/16), k_bf = bf16(k)
// ============================================================
__global__ __launch_bounds__(256) void castqk_kernel(
    const float* __restrict__ q, const float* __restrict__ k,
    unsigned short* __restrict__ q_bf, unsigned short* __restrict__ k_bf) {
  const int total4 = NHH*SEQ*DQ/4;
  for (int i = blockIdx.x*blockDim.x + threadIdx.x; i < total4;
       i += gridDim.x*blockDim.x) {
    float4 a = ((const float4*)q)[i];
    float4 b = ((const float4*)k)[i];
    uint2 oq, ok;
    oq.x = (unsigned)f2bf(a.x*INV_SQRT_D) | ((unsigned)f2bf(a.y*INV_SQRT_D)<<16);
    oq.y = (unsigned)f2bf(a.z*INV_SQRT_D) | ((unsigned)f2bf(a.w*INV_SQRT_D)<<16);
    ok.x = (unsigned)f2bf(b.x) | ((unsigned)f2bf(b.y)<<16);
    ok.y = (unsigned)f2bf(b.z) | ((unsigned)f2bf(b.w)<<16);
    ((uint2*)q_bf)[i] = oq;
    ((uint2*)k_bf)[i] = ok;
  }
}

// ============================================================
// Transpose v[h][t][v] -> vt_bf[h][v][t]
// ============================================================
__global__ __launch_bounds__(256) void transpose_v_kernel(
    const float* __restrict__ v, unsigned short* __restrict__ vt_bf) {
  const int b = blockIdx.x;            // h*512 + tt*16 + vtile
  const int hh = b >> 9;
  const int tt = (b >> 4) & 31;
  const int vtile = b & 15;
  const int tx = threadIdx.x & 31, ty = threadIdx.x >> 5;
  __shared__ float tile[32][33];
  #pragma unroll
  for (int i = 0; i < 4; ++i)
    tile[ty + 8*i][tx] = v[((size_t)(hh*SEQ + tt*32 + ty + 8*i))*DVD + vtile*32 + tx];
  __syncthreads();
  #pragma unroll
  for (int i = 0; i < 4; ++i)
    vt_bf[((size_t)(hh*DVD + vtile*32 + ty + 8*i))*SEQ + tt*32 + tx] =
        f2bf(tile[tx][ty + 8*i]);
}

// ============================================================
// Transpose+weight: kut_bf[h][d][t] = bf16(u[t]*k[h][t][d])
// ============================================================
__global__ __launch_bounds__(256) void transpose_ku_kernel(
    const float* __restrict__ k, const float* __restrict__ ws,
    unsigned short* __restrict__ kut_bf) {
  const int b = blockIdx.x;            // h*256 + tt*8 + dtile
  const int hh = b >> 8;
  const int tt = (b >> 3) & 31;
  const int dtile = b & 7;
  const int tx = threadIdx.x & 31, ty = threadIdx.x >> 5;
  __shared__ float tile[32][33];
  #pragma unroll
  for (int i = 0; i < 4; ++i)
    tile[ty + 8*i][tx] = k[((size_t)(hh*SEQ + tt*32 + ty + 8*i))*DQ + dtile*32 + tx];
  __syncthreads();
  const float uu = ws[WS_UT + hh*SEQ + tt*32 + tx];
  #pragma unroll
  for (int i = 0; i < 4; ++i)
    kut_bf[((size_t)(hh*DQ + dtile*32 + ty + 8*i))*SEQ + tt*32 + tx] =
        f2bf(uu * tile[tx][ty + 8*i]);
}

// ============================================================
// Main attention-style kernel.
// Grid 512: (head, qtile of 64 rows, v-half of 256), LPT-ordered.
// 8 waves. kv-chunk 128. S^T = mfma(K,Q); P through swizzled LDS; PV mfma.
// ============================================================
__global__ __launch_bounds__(512, 2) void attn_kernel(
    const unsigned short* __restrict__ q_bf,
    const unsigned short* __restrict__ k_bf,
    const unsigned short* __restrict__ vt_bf,
    const float* __restrict__ ws,
    float* __restrict__ h_out) {
  const int b = blockIdx.x;
  const int phase = b >> 8;
  const int idx = b & 255;
  const int hh = idx & 15;
  const int vh = (idx >> 4) & 1;
  const int qq = idx >> 5;
  const int qi = phase ? (15 - qq) : qq;      // LPT: shorts first, longs desc
  const int nch = (qi >> 1) + 1;

  const int tid = threadIdx.x;
  const int w = tid >> 6, lane = tid & 63, l31 = lane & 31, hl = lane >> 5;
  const int tsub = w >> 2;        // 0..1: 32-row t-group
  const int sblk = w & 3;         // S-phase s-block
  const int vsub = w & 3;         // PV v-slice (64)

  __shared__ unsigned short Klds[128*256];   // 64 KB  [s][d], 32x16B slots/row
  __shared__ unsigned short Vtlds[256*128];  // 64 KB  [v][s], 16 slots/row
  __shared__ unsigned short Plds[64*128];    // 16 KB  [t][s], 16 slots/row
  __shared__ float c_lds[128];

  const float* a_g  = ws + WS_AT;
  const float* c_g  = ws + WS_CS;
  const float* hd_g = ws + WS_HDEN;

  const int tq = qi*64 + tsub*32 + l31;      // lane's t-column
  const float a_t = a_g[hh*SEQ + tq];

  short8v qfrag[16];
  #pragma unroll
  for (int d = 0; d < 16; ++d)
    qfrag[d] = *(const short8v*)(q_bf + ((size_t)(hh*SEQ + tq))*DQ + d*16 + hl*8);

  f32x16 acc0 = {}, acc1 = {};

  // staging: pre-swizzled global source, linear LDS dest
  auto stage = [&](int c) {
    const int s0 = c*128;
    #pragma unroll
    for (int p = 0; p < 8; ++p) {
      int u = p*512 + tid;
      int row = u >> 5, slot = u & 31;
      const unsigned short* src = k_bf +
          ((size_t)(hh*SEQ + s0 + row))*DQ + ((slot ^ (row & 31))*8);
      gl_lds16(src, (char*)Klds + (p*8 + w)*1024);
    }
    #pragma unroll
    for (int p = 0; p < 8; ++p) {
      int u = p*512 + tid;
      int row = u >> 4, slot = u & 15;
      const unsigned short* src = vt_bf +
          ((size_t)(hh*DVD + vh*256 + row))*SEQ + s0 + ((slot ^ (row & 15))*8);
      gl_lds16(src, (char*)Vtlds + (p*8 + w)*1024);
    }
    if (tid < 128) c_lds[tid] = c_g[hh*SEQ + s0 + tid];
  };

  stage(0);
  __syncthreads();

  for (int c = 0; c < nch; ++c) {
    const int s0 = c*128;
    // ---- S-phase: S^T[s][t] for subtile (sblk, tsub) ----
    f32x16 sacc = {};
    const int srow = sblk*32 + l31;
    #pragma unroll
    for (int d = 0; d < 16; ++d) {
      short8v af = *(const short8v*)&Klds[srow*256 + (((d*2 + hl) ^ (srow & 31))*8)];
      sacc = __builtin_amdgcn_mfma_f32_32x32x16_bf16(af, qfrag[d], sacc, 0, 0, 0);
    }
    // weight, mask, pack bf16, write to Plds (swizzled)
    const int prow = tsub*32 + l31;
    #pragma unroll
    for (int i = 0; i < 8; ++i) {
      const int r0 = 2*i;
      const int sl = sblk*32 + (r0 & 3) + 8*(r0 >> 2) + 4*hl;
      const int sg = s0 + sl;
      const float c0 = c_lds[sl];
      const float c1 = c_lds[sl + 1];
      const float p0 = (sg     <= tq) ? __expf(a_t + c0) * sacc[r0]     : 0.f;
      const float p1 = (sg + 1 <= tq) ? __expf(a_t + c1) * sacc[r0 + 1] : 0.f;
      unsigned int pk;
      asm volatile("v_cvt_pk_bf16_f32 %0, %1, %2" : "=v"(pk) : "v"(p0), "v"(p1));
      const int byte = sl*2;
      const int slot = byte >> 4, rem = byte & 15;
      *(unsigned int*)((char*)Plds + prow*256 + ((slot ^ (prow & 15))<<4) + rem) = pk;
    }
    __syncthreads();

    // ---- PV phase: acc[t][v] += P[t][s] * V[s][v] ----
    #pragma unroll
    for (int ss = 0; ss < 8; ++ss) {
      const int arow = tsub*32 + l31;
      short8v pa = *(const short8v*)&Plds[arow*128 + (((ss*2 + hl) ^ (arow & 15))*8)];
      const int vr0 = vsub*64 + l31;
      const int vr1 = vr0 + 32;
      const int slotB = (ss*2 + hl) ^ (l31 & 15);
      short8v vb0 = *(const short8v*)&Vtlds[vr0*128 + slotB*8];
      short8v vb1 = *(const short8v*)&Vtlds[vr1*128 + slotB*8];
      acc0 = __builtin_amdgcn_mfma_f32_32x32x16_bf16(pa, vb0, acc0, 0, 0, 0);
      acc1 = __builtin_amdgcn_mfma_f32_32x32x16_bf16(pa, vb1, acc1, 0, 0, 0);
    }
    __syncthreads();
    if (c + 1 < nch) { stage(c + 1); __syncthreads(); }
  }

  // ---- epilogue: divide by exact denominator, write h ----
  #pragma unroll
  for (int r = 0; r < 16; ++r) {
    const int tl = tsub*32 + (r & 3) + 8*(r >> 2) + 4*hl;
    const int tg = qi*64 + tl;
    const float inv = 1.0f / hd_g[hh*SEQ + tg];
    const size_t ob = ((size_t)(hh*SEQ + tg))*DVD + vh*256 + vsub*64 + l31;
    h_out[ob]      = acc0[r] * inv;
    h_out[ob + 32] = acc1[r] * inv;
  }
}

// ============================================================
// C GEMM: C[h][d][v] = sum_t kut[h][d][t] * vt[h][v][t]
// ============================================================
__global__ __launch_bounds__(256, 2) void cgemm_kernel(
    const unsigned short* __restrict__ kut,
    const unsigned short* __restrict__ vt,
    float* __restrict__ C_out) {
  const int b = blockIdx.x;       // 16h x 2mt x 8nt
  const int hh = b >> 4;
  const int mt = (b >> 3) & 1;
  const int nt = b & 7;
  const int tid = threadIdx.x;
  const int w = tid >> 6, lane = tid & 63, l31 = lane & 31, hl = lane >> 5;
  const int mr = w >> 1;
  const int nc = w & 1;

  __shared__ unsigned short Alds[128*64];  // 16 KB, [d][t] rows 128B=8 slots
  __shared__ unsigned short Blds[64*64];   //  8 KB, [v][t]

  f32x16 acc0 = {}, acc1 = {};
  for (int c = 0; c < 16; ++c) {
    const int t0 = c*64;
    #pragma unroll
    for (int p = 0; p < 4; ++p) {
      int u = p*256 + tid; int row = u >> 3, slot = u & 7;
      const unsigned short* src = kut +
          ((size_t)(hh*DQ + mt*128 + row))*SEQ + t0 + ((slot ^ (row & 7))*8);
      gl_lds16(src, (char*)Alds + (p*4 + w)*1024);
    }
    #pragma unroll
    for (int p = 0; p < 2; ++p) {
      int u = p*256 + tid; int row = u >> 3, slot = u & 7;
      const unsigned short* src = vt +
          ((size_t)(hh*DVD + nt*64 + row))*SEQ + t0 + ((slot ^ (row & 7))*8);
      gl_lds16(src, (char*)Blds + (p*4 + w)*1024);
    }
    __syncthreads();
    #pragma unroll
    for (int ks = 0; ks < 4; ++ks) {
      const int br = nc*32 + l31;
      short8v bf_ = *(const short8v*)&Blds[br*64 + (((ks*2 + hl) ^ (br & 7))*8)];
      const int ar0 = mr*64 + l31, ar1 = ar0 + 32;
      short8v a0 = *(const short8v*)&Alds[ar0*64 + (((ks*2 + hl) ^ (ar0 & 7))*8)];
      short8v a1 = *(const short8v*)&Alds[ar1*64 + (((ks*2 + hl) ^ (ar1 & 7))*8)];
      acc0 = __builtin_amdgcn_mfma_f32_32x32x16_bf16(a0, bf_, acc0, 0, 0, 0);
      acc1 = __builtin_amdgcn_mfma_f32_32x32x16_bf16(a1, bf_, acc1, 0, 0, 0);
    }
    __syncthreads();
  }
  #pragma unroll
  for (int r = 0; r < 16; ++r) {
    const int dl = (r & 3) + 8*(r >> 2) + 4*hl;
    const int d0 = mt*128 + mr*64 + dl;
    const size_t ob = ((size_t)(hh*DQ + d0))*DVD + nt*64 + nc*32 + l31;
    C_out[ob]            = acc0[r];
    C_out[ob + 32*DVD]   = acc1[r];
  }
}

// ============================================================
// Fallback main kernel (round-1, exact fp32) — used if ws too small
// ============================================================
__global__ __launch_bounds__(256) void mlstm_main_kernel(
    const float* __restrict__ qin, const float* __restrict__ kin,
    const float* __restrict__ vin, const float* __restrict__ ws,
    float* __restrict__ h_out, float* __restrict__ C_out) {
  const int hh  = blockIdx.x >> 4;
  const int ch  = blockIdx.x & 15;
  const int tid = threadIdx.x;
  const int vl  = tid & 31;
  const int dg  = tid >> 5;

  __shared__ float lk[16][DQ];
  __shared__ float lq[16][DQ];
  __shared__ float lv[16][32];
  __shared__ float pbuf[16][8][32];

  float c[32];
  #pragma unroll
  for (int j = 0; j < 32; ++j) c[j] = 0.f;

  for (int ob = 0; ob < 64; ++ob) {
    const int t0 = ob * 16;
    const int gbase = (hh*SEQ + t0) * DQ;
    #pragma unroll 4
    for (int r = 0; r < 16; ++r) {
      lk[r][tid] = kin[gbase + r*DQ + tid];
      lq[r][tid] = qin[gbase + r*DQ + tid];
    }
    {
      const int vgbase = (hh*SEQ + t0) * DVD + ch*32;
      #pragma unroll
      for (int r2 = 0; r2 < 2; ++r2) {
        const int j = r2*256 + tid;
        lv[j >> 5][j & 31] = vin[vgbase + (j >> 5)*DVD + (j & 31)];
      }
    }
    __syncthreads();

    for (int tt = 0; tt < 16; ++tt) {
      const int t = t0 + tt;
      const float fg  = ws[WS_FG + hh*SEQ + t];
      const float ig  = ws[WS_IG + hh*SEQ + t];
      const float ivv = ig * lv[tt][vl];
      const float4* kp = (const float4*)(&lk[tt][dg*32]);
      const float4* qp = (const float4*)(&lq[tt][dg*32]);
      float part = 0.f;
      #pragma unroll
      for (int j4 = 0; j4 < 8; ++j4) {
        const float4 kk = kp[j4];
        const float4 qq = qp[j4];
        c[j4*4+0] = fg*c[j4*4+0] + ivv*kk.x; part += c[j4*4+0]*qq.x;
        c[j4*4+1] = fg*c[j4*4+1] + ivv*kk.y; part += c[j4*4+1]*qq.y;
        c[j4*4+2] = fg*c[j4*4+2] + ivv*kk.z; part += c[j4*4+2]*qq.z;
        c[j4*4+3] = fg*c[j4*4+3] + ivv*kk.w; part += c[j4*4+3]*qq.w;
      }
      pbuf[tt][dg][vl] = part;
    }
    __syncthreads();

    #pragma unroll
    for (int rep = 0; rep < 2; ++rep) {
      const int idx = rep*256 + tid;
      const int tt  = idx >> 5;
      const int v2  = idx & 31;
      float s = 0.f;
      #pragma unroll
      for (int g = 0; g < 8; ++g) s += pbuf[tt][g][v2];
      const float hd = ws[WS_HDEN + hh*SEQ + t0 + tt];
      h_out[(hh*SEQ + t0 + tt)*DVD + ch*32 + v2] = s * INV_SQRT_D / hd;
    }
  }

  #pragma unroll
  for (int j = 0; j < 32; ++j) {
    const int d = dg*32 + j;
    C_out[(hh*DQ + d)*DVD + ch*32 + vl] = c[j];
  }
}

// ============================================================
extern "C" void kernel_launch(void* const* d_in, const int* in_sizes, int n_in,
                              void* d_out, int out_size, void* d_ws, size_t ws_size,
                              hipStream_t stream) {
  const float* q  = (const float*)d_in[0];
  const float* k  = (const float*)d_in[1];
  const float* v  = (const float*)d_in[2];
  const float* ip = (const float*)d_in[3];
  const float* fp = (const float*)d_in[4];

  float* h_out = (float*)d_out;                       // [16][1024][512]
  float* C_out = h_out + (size_t)NHH*SEQ*DVD;         // [16][256][512]
  float* n_out = C_out + (size_t)NHH*DQ*DVD;          // [16][256]
  float* m_out = n_out + NHH*DQ;                      // [16]
  float* ws    = (float*)d_ws;

  gates_kernel<<<NHH, 1024, 0, stream>>>(ip, fp, ws, m_out);
  bvec_kernel<<<NHH*16, 256, 0, stream>>>(k, ws);
  nscan_kernel<<<NHH, 256, 0, stream>>>(ws, n_out);
  hden_kernel<<<NHH*16, 256, 0, stream>>>(k, q, ws);

  if (ws_size >= WS_NEED) {
    unsigned short* q_bf  = (unsigned short*)((char*)d_ws + QBF_OFF);
    unsigned short* k_bf  = (unsigned short*)((char*)d_ws + KBF_OFF);
    unsigned short* vt_bf = (unsigned short*)((char*)d_ws + VTB_OFF);
    unsigned short* kut   = (unsigned short*)((char*)d_ws + KUT_OFF);

    castqk_kernel<<<2048, 256, 0, stream>>>(q, k, q_bf, k_bf);
    transpose_v_kernel<<<NHH*32*16, 256, 0, stream>>>(v, vt_bf);
    transpose_ku_kernel<<<NHH*32*8, 256, 0, stream>>>(k, ws, kut);
    attn_kernel<<<512, 512, 0, stream>>>(q_bf, k_bf, vt_bf, ws, h_out);
    cgemm_kernel<<<256, 256, 0, stream>>>(kut, vt_bf, C_out);
  } else {
    mlstm_main_kernel<<<NHH*16, 256, 0, stream>>>(q, k, v, ws, h_out, C_out);
  }
}